// Round 2
// baseline (100.836 us; speedup 1.0000x reference)
//
#include <hip/hip_runtime.h>
#include <math.h>

// Problem constants (match reference)
#define Hh 121
#define Ww 121
#define NPI 200          // N_INTERP
#define Bb 8
#define Ee 225
#define NPIX (Hh * Ww)   // 14641
#define PBLK 58          // ceil(14641 / 256) pixel-blocks per batch

#define RPD      280.0f                  // RET_PER_DVA
#define XLOWc   (-15.0f * 280.0f)        // -4200
#define STEPc   (8400.0f / 199.0f)       // STEP_X == STEP_Y
#define ODXc    (15.5f * 280.0f)         // OD_OFF_X = 4340
#define PIc      3.14159265358979323846f
#define TEMP1c  (4.0f * PIc)
#define L2E      1.44269504088896340736f    // log2(e)
#define NHL     (-0.72134752044448170368f)  // -0.5 * log2(e)
#define CULL_T   20.0f   // cull when |t| (log2 units) provably > 20 -> contrib < bright*2^-20

#if __has_builtin(__builtin_amdgcn_exp2f)
#define EXP2F(x) __builtin_amdgcn_exp2f(x)
#else
#define EXP2F(x) exp2f(x)
#endif

// Fused kernel with per-wave electrode culling:
//   phase 1 (threads 0..224): per-(b,e) precompute -> LDS:
//     sbox[e] = {cxlo, cxhi, cylo, cyhi}  conservative influence AABB
//     sval[e] = {cx, cy, A, B}            t = A*dx^2 + B*dx*dy + C*dy^2 (log2 units)
//     svw[e]  = {C, bright}
//     Box from min-eigenvalue lambda of -t's quadratic form: ||d|| > sqrt(T/lambda)
//     => |t| > T. Chebyshev test (AABB) is conservative vs Euclidean.
//     bright==0 (amp <= AMP_CUTOFF) -> empty box, always culled.
//   phase 2: thread = one pixel; loop electrodes; wave-uniform AABB test fully
//     skips the exp-body for electrodes that can't touch this wave's pixels.
extern "C" __global__ void __launch_bounds__(256)
mvg_fused(const float* __restrict__ stim, const float* __restrict__ params,
          const float* __restrict__ elec_x, const float* __restrict__ elec_y,
          const float* __restrict__ slopes, float* __restrict__ out)
{
    __shared__ __align__(16) float4 sbox[Ee];
    __shared__ __align__(16) float4 sval[Ee];
    __shared__ __align__(8)  float2 svw[Ee];

    const int b   = blockIdx.y;
    const int tid = threadIdx.x;

    if (tid < Ee) {
        const float* p = params + b * 13;
        const float rho = p[0], lam = p[1], osc = p[2];
        const float a0 = p[3], a1 = p[4], a2 = p[5], a3 = p[6], a4 = p[7];
        const float impx = p[8], impy = p[9], rot = p[10], locx = p[11];

        const float cr = cosf(rot), sr = sinf(rot);
        const float exl = elec_x[tid], eyl = elec_y[tid];
        const float exv = exl * cr - eyl * sr + impx;
        const float eyv = exl * sr + eyl * cr + impy;

        // bilinear interp of slopes at (qx, qy)
        const float offx = locx - ODXc;
        const float qx = (exv - offx - XLOWc) / STEPc;
        const float qy = (eyv - XLOWc) / STEPc;            // YLOW == XLOW
        const float fx = fminf(fmaxf(floorf(qx), 0.0f), (float)(NPI - 2));
        const float fy = fminf(fmaxf(floorf(qy), 0.0f), (float)(NPI - 2));
        const int ix = (int)fx, iy = (int)fy;
        const float ax = fminf(fmaxf(qx - fx, 0.0f), 1.0f);
        const float ay = fminf(fmaxf(qy - fy, 0.0f), 1.0f);
        const float g00 = slopes[iy * NPI + ix];
        const float g01 = slopes[iy * NPI + ix + 1];
        const float g10 = slopes[(iy + 1) * NPI + ix];
        const float g11 = slopes[(iy + 1) * NPI + ix + 1];
        const float top = g00 + ax * (g01 - g00);
        const float bot = g10 + ax * (g11 - g10);
        float th = top + ay * (bot - top);
        th = (th < -0.5f * PIc) ? th + PIc : th;
        th *= osc;

        const float* st = stim + (b * Ee + tid) * 3;
        const float freq = st[0], amp = st[1], pdur = st[2];

        const float rho_s = fmaxf(rho * amp * a3, 1.0f);
        float lam_s = lam * powf(0.45f, -a4) * powf(pdur, a4);
        lam_s = fminf(fmaxf(lam_s, 0.0f), 0.99f);
        const float bright =
            (amp > 0.25f) ? (a0 * powf(fmaxf(amp, 1e-5f), a1) + a2 * freq) : 0.0f;

        const float temp2 = sqrtf(1.0f - lam_s * lam_s);
        const float sy_ = rho_s / (TEMP1c * temp2);
        const float sx_ = rho_s * temp2 / TEMP1c;
        const float s = sinf(th), c = cosf(th);
        const float cov00 = sx_ * c * c + sy_ * s * s;
        const float cov01 = (sx_ - sy_) * s * c;
        const float cov11 = sx_ * s * s + sy_ * c * c;
        const float det = cov00 * cov11 - cov01 * cov01;
        const float i00 = cov11 / det;
        const float i01 = -cov01 / det;
        const float i11 = cov00 / det;

        const float cx = (exv / RPD + 15.0f) * 4.0f;
        const float cy = (float)Hh - (eyv / RPD + 15.0f) * 4.0f;

        // t = A dx^2 + B dx dy + C dy^2  (already includes -0.5*log2e)
        const float A = i00 * NHL;
        const float B = i01 * 2.0f * NHL;
        const float C = i11 * NHL;

        // min eigenvalue of the positive form (-t):  a dx^2 + b dx dy + c dy^2
        const float a = -A, bq = -B, cc = -C;
        const float lam_min = 0.5f * ((a + cc) - sqrtf((a - cc) * (a - cc) + bq * bq));
        float R;
        if (bright != 0.0f && lam_min > 0.0f) {
            R = sqrtf(CULL_T / lam_min) + 0.5f;
        } else if (bright != 0.0f) {
            R = 1e9f;   // degenerate: never cull
        } else {
            R = -1e9f;  // zero brightness: always cull
        }

        sbox[tid] = make_float4(cx - R, cx + R, cy - R, cy + R);
        sval[tid] = make_float4(cx, cy, A, B);
        svw[tid]  = make_float2(C, bright);
    }
    __syncthreads();

    const int pix = blockIdx.x * 256 + tid;

    // Wave pixel AABB (uniform within each wave)
    const int wv = tid >> 6;
    int p0 = blockIdx.x * 256 + (wv << 6);
    int p1 = p0 + 63;
    p0 = p0 < (NPIX - 1) ? p0 : (NPIX - 1);
    p1 = p1 < (NPIX - 1) ? p1 : (NPIX - 1);
    const int i0 = p0 / Ww, i1 = p1 / Ww;
    const float pymin = (float)(Ww - 1 - i1);
    const float pymax = (float)(Ww - 1 - i0);
    float pxmin, pxmax;
    if (i0 == i1) { pxmin = (float)(p0 - i0 * Ww); pxmax = (float)(p1 - i0 * Ww); }
    else          { pxmin = 0.0f; pxmax = (float)(Ww - 1); }

    if (pix < NPIX) {
        const int i = pix / Ww;
        const int j = pix - i * Ww;
        const float px = (float)j;
        const float py = (float)(Ww - 1 - i);

        float acc = 0.0f;
        #pragma unroll 1
        for (int e = 0; e < Ee; ++e) {
            const float4 bx = sbox[e];
            // wave-uniform overlap test -> full skip via execz branch
            if (bx.y >= pxmin && bx.x <= pxmax && bx.w >= pymin && bx.z <= pymax) {
                const float4 v = sval[e];
                const float2 w = svw[e];
                const float dx = px - v.x;
                const float dy = py - v.y;
                float u = dy * v.w;            // B*dy
                u = fmaf(dx, v.z, u);          // A*dx + B*dy
                const float pq = dx * u;
                const float vv = dy * w.x;     // C*dy
                const float t = fmaf(dy, vv, pq);
                acc = fmaf(w.y, EXP2F(t), acc);
            }
        }
        out[b * NPIX + pix] = acc;
    }
}

extern "C" void kernel_launch(void* const* d_in, const int* in_sizes, int n_in,
                              void* d_out, int out_size, void* d_ws, size_t ws_size,
                              hipStream_t stream) {
    const float* stim   = (const float*)d_in[0];  // (8, 225, 3)
    const float* params = (const float*)d_in[1];  // (8, 13)
    const float* ex     = (const float*)d_in[2];  // (1, 225)
    const float* ey     = (const float*)d_in[3];  // (1, 225)
    const float* slopes = (const float*)d_in[4];  // (200, 200)
    // d_in[5] = pixelgrid: unused, indices derived analytically
    float* out = (float*)d_out;                   // (8, 121, 121) fp32

    dim3 grid(PBLK, Bb);  // 58 pixel-chunks x 8 batches
    mvg_fused<<<grid, 256, 0, stream>>>(stim, params, ex, ey, slopes, out);
}

// Round 3
// 73.979 us; speedup vs baseline: 1.3630x; 1.3630x over previous
//
#include <hip/hip_runtime.h>
#include <math.h>

// Problem constants (match reference)
#define Hh 121
#define Ww 121
#define NPI 200          // N_INTERP
#define Bb 8
#define Ee 225
#define NPIX (Hh * Ww)   // 14641
#define TS 16            // pixel tile side
#define XT 8             // ceil(121/16)
#define YT 8

#define RPD      280.0f                  // RET_PER_DVA
#define XLOWc   (-4200.0f)               // XRANGE0 * RET_PER_DVA
#define STEPc   (8400.0f / 199.0f)       // STEP_X == STEP_Y
#define ODXc     4340.0f                 // OD_OFF_X
#define PIc      3.14159265358979323846f
#define TEMP1c  (4.0f * PIc)
#define NHL     (-0.72134752044448170368f)  // -0.5 * log2(e)
#define CULL_T   20.0f   // drop terms provably < bright * 2^-20
#define NL2_045  1.15200309344504995f    // -log2(0.45)

#if __has_builtin(__builtin_amdgcn_exp2f)
#define EXP2F(x) __builtin_amdgcn_exp2f(x)
#else
#define EXP2F(x) exp2f(x)
#endif
#if __has_builtin(__builtin_amdgcn_logf)
#define LOG2F(x) __builtin_amdgcn_logf(x)
#else
#define LOG2F(x) log2f(x)
#endif

#define MAXC 232   // 225 max survivors + 4 zero-pad

// Round 3 structure:
//  phase 1 (tid<225): per-(b,e) record computed in registers; survival test vs
//    this block's 16x16 pixel AABB (min-eigenvalue cull radius R, Chebyshev
//    conservative); survivors atomicAdd-compact their RECORD into LDS.
//  phase 2: pad with 4 zero-records (bright=0 -> exp2(0)*0 = 0) so the
//    electrode loop runs branch-free at a multiple of 4.
//  phase 3: thread = one pixel of the tile; unroll-4 branch-free loop,
//    8 independent broadcast LDS reads in flight per group (ILP hides LDS
//    latency at ~1.8 waves/SIMD occupancy).
extern "C" __global__ void __launch_bounds__(256)
mvg_fused(const float* __restrict__ stim, const float* __restrict__ params,
          const float* __restrict__ elec_x, const float* __restrict__ elec_y,
          const float* __restrict__ slopes, float* __restrict__ out)
{
    __shared__ __align__(16) float4 scA[MAXC];  // {cx, cy, A, B}
    __shared__ __align__(8)  float2 scB[MAXC];  // {C, bright}
    __shared__ int scnt;

    const int b   = blockIdx.z;
    const int txb = blockIdx.x;
    const int tyb = blockIdx.y;
    const int tid = threadIdx.x;

    if (tid == 0) scnt = 0;
    __syncthreads();

    // Block pixel AABB (clamped to the image)
    const int   jmin = txb * TS;
    const int   jmax = min(jmin + TS - 1, Ww - 1);
    const int   imin = tyb * TS;
    const int   imax = min(imin + TS - 1, Hh - 1);
    const float pxminf = (float)jmin, pxmaxf = (float)jmax;
    const float pyminf = (float)(Hh - 1 - imax), pymaxf = (float)(Hh - 1 - imin);

    if (tid < Ee) {
        const float* p = params + b * 13;
        const float rho = p[0], lam = p[1], osc = p[2];
        const float pa0 = p[3], pa1 = p[4], pa2 = p[5], pa3 = p[6], pa4 = p[7];
        const float impx = p[8], impy = p[9], rot = p[10], locx = p[11];

        const float cr = cosf(rot), sr = sinf(rot);
        const float exl = elec_x[tid], eyl = elec_y[tid];
        const float exv = exl * cr - eyl * sr + impx;
        const float eyv = exl * sr + eyl * cr + impy;

        // bilinear interp of slopes at (qx, qy)
        const float offx = locx - ODXc;
        const float qx = (exv - offx - XLOWc) / STEPc;
        const float qy = (eyv - XLOWc) / STEPc;            // YLOW == XLOW
        const float fx = fminf(fmaxf(floorf(qx), 0.0f), (float)(NPI - 2));
        const float fy = fminf(fmaxf(floorf(qy), 0.0f), (float)(NPI - 2));
        const int ix = (int)fx, iy = (int)fy;
        const float ax = fminf(fmaxf(qx - fx, 0.0f), 1.0f);
        const float ay = fminf(fmaxf(qy - fy, 0.0f), 1.0f);
        const float g00 = slopes[iy * NPI + ix];
        const float g01 = slopes[iy * NPI + ix + 1];
        const float g10 = slopes[(iy + 1) * NPI + ix];
        const float g11 = slopes[(iy + 1) * NPI + ix + 1];
        const float top = g00 + ax * (g01 - g00);
        const float bot = g10 + ax * (g11 - g10);
        float th = top + ay * (bot - top);
        th = (th < -0.5f * PIc) ? th + PIc : th;
        th *= osc;

        const float* st = stim + (b * Ee + tid) * 3;
        const float freq = st[0], amp = st[1], pdur = st[2];

        const float rho_s = fmaxf(rho * amp * pa3, 1.0f);
        // lam * 0.45^(-a4) * pdur^a4 = lam * exp2(a4*(log2(pdur) - log2(0.45)))
        float lam_s = lam * EXP2F(pa4 * (LOG2F(pdur) + NL2_045));
        lam_s = fminf(fmaxf(lam_s, 0.0f), 0.99f);
        // a0 * amp^a1 + a2*freq  (amp^a1 = exp2(a1*log2(amp)))
        const float bright =
            (amp > 0.25f)
                ? (pa0 * EXP2F(pa1 * LOG2F(fmaxf(amp, 1e-5f))) + pa2 * freq)
                : 0.0f;

        const float temp2 = sqrtf(1.0f - lam_s * lam_s);
        const float sy_ = rho_s / (TEMP1c * temp2);
        const float sx_ = rho_s * temp2 / TEMP1c;
        const float s = sinf(th), c = cosf(th);
        const float cov00 = sx_ * c * c + sy_ * s * s;
        const float cov01 = (sx_ - sy_) * s * c;
        const float cov11 = sx_ * s * s + sy_ * c * c;
        const float det = cov00 * cov11 - cov01 * cov01;
        const float i00 = cov11 / det;
        const float i01 = -cov01 / det;
        const float i11 = cov00 / det;

        const float cx = (exv / RPD + 15.0f) * 4.0f;
        const float cy = (float)Hh - (eyv / RPD + 15.0f) * 4.0f;

        // t = A dx^2 + B dx dy + C dy^2 (log2 units, -0.5*log2e folded in)
        const float A = i00 * NHL;
        const float B = i01 * 2.0f * NHL;
        const float C = i11 * NHL;

        // cull radius from min eigenvalue of the positive form (-t)
        const float a = -A, bq = -B, cc = -C;
        const float lam_min = 0.5f * ((a + cc) - sqrtf((a - cc) * (a - cc) + bq * bq));
        float R;
        if (bright != 0.0f && lam_min > 0.0f)      R = sqrtf(CULL_T / lam_min) + 0.5f;
        else if (bright != 0.0f)                   R = 1e9f;   // degenerate: keep
        else                                       R = -1e9f;  // dark: drop

        const bool live = (cx + R >= pxminf) && (cx - R <= pxmaxf) &&
                          (cy + R >= pyminf) && (cy - R <= pymaxf);
        if (live) {
            const int pos = atomicAdd(&scnt, 1);
            scA[pos] = make_float4(cx, cy, A, B);
            scB[pos] = make_float2(C, bright);
        }
    }
    __syncthreads();

    const int cnt = scnt;
    if (tid < 4) {
        scA[cnt + tid] = make_float4(0.0f, 0.0f, 0.0f, 0.0f);
        scB[cnt + tid] = make_float2(0.0f, 0.0f);
    }
    __syncthreads();
    const int n = (cnt + 3) & ~3;

    // thread -> pixel of this tile
    const int lx = tid & (TS - 1);
    const int ly = tid >> 4;
    const int j  = jmin + lx;
    const int i  = imin + ly;
    const float px = (float)j;
    const float py = (float)(Hh - 1 - i);

    float ac0 = 0.0f, ac1 = 0.0f, ac2 = 0.0f, ac3 = 0.0f;

#define BODY(k, acc) {                                          \
        const float4 v = scA[e + (k)];                          \
        const float2 w = scB[e + (k)];                          \
        const float dx = px - v.x;                              \
        const float dy = py - v.y;                              \
        const float u  = fmaf(dx, v.z, dy * v.w);               \
        const float t  = fmaf(dy * dy, w.x, dx * u);            \
        acc = fmaf(w.y, EXP2F(t), acc);                         \
    }

    #pragma unroll 1
    for (int e = 0; e < n; e += 4) {
        BODY(0, ac0)
        BODY(1, ac1)
        BODY(2, ac2)
        BODY(3, ac3)
    }
#undef BODY

    if (i < Hh && j < Ww)
        out[b * NPIX + i * Ww + j] = (ac0 + ac1) + (ac2 + ac3);
}

extern "C" void kernel_launch(void* const* d_in, const int* in_sizes, int n_in,
                              void* d_out, int out_size, void* d_ws, size_t ws_size,
                              hipStream_t stream) {
    const float* stim   = (const float*)d_in[0];  // (8, 225, 3)
    const float* params = (const float*)d_in[1];  // (8, 13)
    const float* ex     = (const float*)d_in[2];  // (1, 225)
    const float* ey     = (const float*)d_in[3];  // (1, 225)
    const float* slopes = (const float*)d_in[4];  // (200, 200)
    // d_in[5] = pixelgrid: unused, indices derived analytically
    float* out = (float*)d_out;                   // (8, 121, 121) fp32

    dim3 grid(XT, YT, Bb);  // 8x8 pixel tiles x 8 batches = 512 blocks
    mvg_fused<<<grid, 256, 0, stream>>>(stim, params, ex, ey, slopes, out);
}